// Round 2
// baseline (16526.790 us; speedup 1.0000x reference)
//
#include <hip/hip_runtime.h>
#include <hip/hip_bf16.h>
#include <hip/hip_cooperative_groups.h>
#include <stdint.h>

namespace cg = cooperative_groups;

// Sizes (fixed by the problem)
#define BB 512      // batch
#define TT 128      // seq len
#define DD 1024     // input dim / hidden
#define HH 1024
#define G3 3072     // 3*H
#define TC 32       // time chunk
#define NCH (TT/TC)

typedef __bf16 bft;
typedef __bf16 bf16x8 __attribute__((ext_vector_type(8)));
typedef float f32x4 __attribute__((ext_vector_type(4)));

// async global->LDS, 16B per lane. lds base must be wave-uniform; lane i's data
// lands at base + i*16, so lane i's global ptr must be the data for that slot.
__device__ __forceinline__ void gl_lds16(const bft* g, void* lds_base_uniform) {
  __builtin_amdgcn_global_load_lds(
      (const __attribute__((address_space(1))) void*)g,
      (__attribute__((address_space(3))) void*)lds_base_uniform,
      16, 0, 0);
}

// ---------------- fp32 -> bf16 convert (vectorized 8/thread) ----------------
__global__ void k_cvt(const float* __restrict__ in, bft* __restrict__ out, long n) {
  long i = ((long)blockIdx.x * blockDim.x + threadIdx.x) * 8;
  long stride = (long)gridDim.x * blockDim.x * 8;
  for (; i < n; i += stride) {
    float4 a = *(const float4*)(in + i);
    float4 b = *(const float4*)(in + i + 4);
    bf16x8 r;
    r[0] = (bft)a.x; r[1] = (bft)a.y; r[2] = (bft)a.z; r[3] = (bft)a.w;
    r[4] = (bft)b.x; r[5] = (bft)b.y; r[6] = (bft)b.z; r[7] = (bft)b.w;
    *(bf16x8*)(out + i) = r;
  }
}

// ---------------- generic bf16 GEMM: C[m,n] = sum_k A[m,k]*W[n,k] + bias[n] --
// BM=BN=128, BK=64, 256 threads (4 waves as 2x2, each wave 64x64 = 4x4 frags).
// CHUNKED: A row m maps to global row (m>>5)*TT + t0 + (m&31)  (b,t packing).
// EPI==0: store bf16 (x_proj). EPI==1: store fp32 silu(v) (logits).
template<bool CHUNKED, int EPI>
__launch_bounds__(256)
__global__ void k_gemm(const bft* __restrict__ A, long lda,
                       const bft* __restrict__ W, long ldw,
                       const float* __restrict__ bias,
                       void* __restrict__ Cout, long ldc,
                       int t0, int K) {
  __shared__ unsigned char sm[32768];   // A tile 16KB | W tile 16KB
  const int tid  = threadIdx.x;
  const int lane = tid & 63;
  const int wid  = tid >> 6;
  const int m0 = blockIdx.y * 128;
  const int n0 = blockIdx.x * 128;
  const int wm = wid >> 1, wn = wid & 1;

  f32x4 acc[4][4] = {};

  for (int k0 = 0; k0 < K; k0 += 64) {
#pragma unroll
    for (int s = 0; s < 4; ++s) {
      int seg = wid * 4 + s;
      int row = seg * 8 + (lane >> 3);
      int cbs = ((lane & 7) * 16) ^ ((row & 7) << 4);
      long grow = CHUNKED ? ((long)(row + m0 >> 5) * TT + t0 + ((row + m0) & 31))
                          : (long)(m0 + row);
      gl_lds16(A + grow * lda + k0 + (cbs >> 1), sm + seg * 1024);
    }
#pragma unroll
    for (int s = 0; s < 4; ++s) {
      int seg = wid * 4 + s;
      int row = seg * 8 + (lane >> 3);
      int cbs = ((lane & 7) * 16) ^ ((row & 7) << 4);
      gl_lds16(W + (long)(n0 + row) * ldw + k0 + (cbs >> 1), sm + 16384 + seg * 1024);
    }
    __syncthreads();
#pragma unroll
    for (int ks = 0; ks < 2; ++ks) {
      int kb = ks * 64 + (lane >> 4) * 16;
      bf16x8 aF[4], bF[4];
#pragma unroll
      for (int mi = 0; mi < 4; ++mi) {
        int row = wm * 64 + mi * 16 + (lane & 15);
        aF[mi] = *(const bf16x8*)(sm + row * 128 + (kb ^ ((row & 7) << 4)));
      }
#pragma unroll
      for (int ni = 0; ni < 4; ++ni) {
        int row = wn * 64 + ni * 16 + (lane & 15);
        bF[ni] = *(const bf16x8*)(sm + 16384 + row * 128 + (kb ^ ((row & 7) << 4)));
      }
#pragma unroll
      for (int mi = 0; mi < 4; ++mi)
#pragma unroll
        for (int ni = 0; ni < 4; ++ni)
          acc[mi][ni] = __builtin_amdgcn_mfma_f32_16x16x32_bf16(aF[mi], bF[ni], acc[mi][ni], 0, 0, 0);
    }
    __syncthreads();
  }

#pragma unroll
  for (int mi = 0; mi < 4; ++mi)
#pragma unroll
    for (int ni = 0; ni < 4; ++ni) {
      int col = n0 + wn * 64 + ni * 16 + (lane & 15);
      float bv = bias[col];
#pragma unroll
      for (int r = 0; r < 4; ++r) {
        long row = m0 + wm * 64 + mi * 16 + (lane >> 4) * 4 + r;
        float v = acc[mi][ni][r] + bv;
        if (EPI == 0) {
          ((bft*)Cout)[row * ldc + col] = (bft)v;
        } else {
          ((float*)Cout)[row * ldc + col] = v / (1.f + expf(-v));
        }
      }
    }
}

// ---------------- persistent GRU chunk kernel (cooperative) ----------------
// 256 WGs = 64 n-tiles x 4 m-tiles. Each WG: n-slice of 16 h-cols (48 whh rows
// incl. 3 gates) weight-stationary in LDS (96KB, XOR-swizzled); m-slice of 128
// batch rows. Runs TC=32 steps with grid.sync() between steps.
// L==0: A-src = h-seq in xseq (in-place), writes h to xseq (bf16) + hf parity.
// L==1: A-src/dst = hb parity buffers (bf16) + hf parity.
template<int L>
__launch_bounds__(256, 1)
__global__ void k_persist(const bft* __restrict__ whh, const float* __restrict__ bhh,
                          const bft* __restrict__ xp, bft* __restrict__ xseq,
                          bft* __restrict__ hb0, bft* __restrict__ hb1,
                          float* __restrict__ hf0, float* __restrict__ hf1,
                          int t0) {
  cg::grid_group grid = cg::this_grid();
  __shared__ unsigned char sm[131072];          // W 96KB | A dbuf 2x16KB
  unsigned char* smW = sm;
  unsigned char* smA = sm + 98304;

  const int tid  = threadIdx.x;
  const int lane = tid & 63;
  const int wid  = tid >> 6;
  const int bid  = blockIdx.x;
  // XCD-aware: bid%8 = XCD; give each XCD 8 contiguous n-tiles x 4 m-tiles.
  const int xcd = bid & 7, loc = bid >> 3;
  const int nt = xcd * 8 + (loc & 7);   // 0..63
  const int mt = loc >> 3;              // 0..3
  const int j0 = nt * 16;
  const int m0 = mt * 128;
  const int j  = j0 + (lane & 15);

  // ---- load W slice into LDS (once): rows r in [0,48), r -> gate r>>4, col j0+(r&15)
#pragma unroll
  for (int s8 = 0; s8 < 24; ++s8) {
    int s = wid * 24 + s8;
    int row = s >> 1;
    int half = s & 1;
    int hb = half * 1024 + lane * 16;               // byte within 2048B row
    int sb = hb ^ ((row & 7) << 4);                 // pre-swizzled source byte
    long grow = (long)(row >> 4) * 1024 + j0 + (row & 15);
    gl_lds16(whh + grow * 1024 + (sb >> 1), smW + s * 1024);
  }
  asm volatile("s_waitcnt vmcnt(0)" ::: "memory");
  __builtin_amdgcn_s_barrier();

  const float br = bhh[j], bz = bhh[1024 + j], bn = bhh[2048 + j];

  auto stageA = [&](const bft* base, long stride, int k0, int bufsel) {
    unsigned char* dst = smA + bufsel * 16384;
#pragma unroll
    for (int si = 0; si < 4; ++si) {
      int seg = wid * 4 + si;
      int row = seg * 8 + (lane >> 3);
      int cb = ((lane & 7) * 16) ^ ((row & 7) << 4);
      gl_lds16(base + (long)(m0 + row) * stride + k0 + (cb >> 1), dst + seg * 1024);
    }
  };

  for (int s = 0; s < TC; ++s) {
    const int t = t0 + s;
    if (s) { __threadfence(); grid.sync(); }

    const bft* Ab; long Ast;
    if (L == 0) {
      if (t == 0) { Ab = hb1; Ast = HH; }
      else        { Ab = xseq + (long)(t - 1) * DD; Ast = (long)TT * DD; }
    } else {
      Ab = (t & 1) ? hb0 : hb1; Ast = HH;
    }

    stageA(Ab, Ast, 0, 0);

    // prefetch cell operands (latency hides under K-loop)
    const float* hfs = (t & 1) ? hf0 : hf1;
    float xg[3][2][4], hp[2][4];
#pragma unroll
    for (int mi = 0; mi < 2; ++mi)
#pragma unroll
      for (int r = 0; r < 4; ++r) {
        long b = m0 + wid * 32 + mi * 16 + (lane >> 4) * 4 + r;
        long xrow = (b * TC + s) * (long)G3 + j;
        xg[0][mi][r] = (float)xp[xrow];
        xg[1][mi][r] = (float)xp[xrow + 1024];
        xg[2][mi][r] = (float)xp[xrow + 2048];
        hp[mi][r] = hfs[b * HH + j];
      }

    f32x4 acc[3][2] = {};
#pragma unroll
    for (int k = 0; k < 16; ++k) {
      __builtin_amdgcn_s_barrier();
      if (k < 15) {
        stageA(Ab, Ast, (k + 1) * 64, (k + 1) & 1);
        asm volatile("s_waitcnt vmcnt(4)" ::: "memory");
      } else {
        asm volatile("s_waitcnt vmcnt(0)" ::: "memory");
      }
      __builtin_amdgcn_s_barrier();
      __builtin_amdgcn_sched_barrier(0);
      const unsigned char* Abuf = smA + (k & 1) * 16384;
#pragma unroll
      for (int ks = 0; ks < 2; ++ks) {
        int kb = ks * 64 + (lane >> 4) * 16;
        bf16x8 aF[2], bF[3];
#pragma unroll
        for (int mi = 0; mi < 2; ++mi) {
          int row = wid * 32 + mi * 16 + (lane & 15);
          aF[mi] = *(const bf16x8*)(Abuf + row * 128 + (kb ^ ((row & 7) << 4)));
        }
#pragma unroll
        for (int g = 0; g < 3; ++g) {
          int wrow = g * 16 + (lane & 15);
          bF[g] = *(const bf16x8*)(smW + wrow * 2048 + ((k * 128 + kb) ^ ((wrow & 7) << 4)));
        }
#pragma unroll
        for (int g = 0; g < 3; ++g)
#pragma unroll
          for (int mi = 0; mi < 2; ++mi)
            acc[g][mi] = __builtin_amdgcn_mfma_f32_16x16x32_bf16(aF[mi], bF[g], acc[g][mi], 0, 0, 0);
      }
    }

    // epilogue: GRU cell
    float* hfd = (t & 1) ? hf1 : hf0;
    bft* hbd = (t & 1) ? hb1 : hb0;
#pragma unroll
    for (int mi = 0; mi < 2; ++mi)
#pragma unroll
      for (int r = 0; r < 4; ++r) {
        long b = m0 + wid * 32 + mi * 16 + (lane >> 4) * 4 + r;
        float hr = acc[0][mi][r] + br;
        float hz = acc[1][mi][r] + bz;
        float hn = acc[2][mi][r] + bn;
        float rg = 1.f / (1.f + expf(-(xg[0][mi][r] + hr)));
        float zg = 1.f / (1.f + expf(-(xg[1][mi][r] + hz)));
        float ng = tanhf(xg[2][mi][r] + rg * hn);
        float hv = (1.f - zg) * ng + zg * hp[mi][r];
        hfd[b * HH + j] = hv;
        if (L == 0) xseq[b * (long)TT * DD + (long)t * DD + j] = (bft)hv;
        else        hbd[b * HH + j] = (bft)hv;
      }
  }
}

// ---------------- softmax + rebalance (one block per row) ----------------
__device__ __forceinline__ float blk_sum(float v, float* red, int tid) {
#pragma unroll
  for (int o = 32; o; o >>= 1) v += __shfl_xor(v, o);
  if ((tid & 63) == 0) red[tid >> 6] = v;
  __syncthreads();
  v = red[0] + red[1] + red[2] + red[3];
  __syncthreads();
  return v;
}
__device__ __forceinline__ float blk_max(float v, float* red, int tid) {
#pragma unroll
  for (int o = 32; o; o >>= 1) v = fmaxf(v, __shfl_xor(v, o));
  if ((tid & 63) == 0) red[tid >> 6] = v;
  __syncthreads();
  v = fmaxf(fmaxf(red[0], red[1]), fmaxf(red[2], red[3]));
  __syncthreads();
  return v;
}

__launch_bounds__(256)
__global__ void k_smrebal(const float* __restrict__ logits, float* __restrict__ out) {
  __shared__ float red[4];
  const int tid = threadIdx.x;
  const long row = blockIdx.x;
  const float ub = 0.2f, lb = 0.0f;
  float4 lv = *(const float4*)(logits + row * 1024 + tid * 4);

  float m = fmaxf(fmaxf(lv.x, lv.y), fmaxf(lv.z, lv.w));
  m = blk_max(m, red, tid);
  float e[4] = {expf(lv.x - m), expf(lv.y - m), expf(lv.z - m), expf(lv.w - m)};
  float S = blk_sum(e[0] + e[1] + e[2] + e[3], red, tid);

  float old_[4], wc[4];
#pragma unroll
  for (int k = 0; k < 4; ++k) {
    float p = e[k] / S;
    old_[k] = p;
    wc[k] = fminf(fmaxf(p, lb), ub);
  }
  bool done = false;
  for (int it = 0; it < 32 && !done; ++it) {
    float d3 = 0.f, cnt = 0.f, nsum = 0.f;
#pragma unroll
    for (int k = 0; k < 4; ++k) {
      d3 += old_[k] - wc[k];
      bool mk = (wc[k] != ub);
      cnt += mk ? 1.f : 0.f;
      nsum += mk ? wc[k] : 0.f;
    }
    float leftover = blk_sum(d3, red, tid);
    float num = blk_sum(cnt, red, tid);
    float nom_sum = blk_sum(nsum, red, tid);
    float denom = (nom_sum == 0.f) ? 1.f : nom_sum;
    float wcn[4], mx = -1e30f;
#pragma unroll
    for (int k = 0; k < 4; ++k) {
      bool mk = (wc[k] != ub);
      wcn[k] = mk ? wc[k] + leftover * wc[k] / denom : wc[k];
      mx = fmaxf(mx, wcn[k]);
    }
    float gmx = blk_max(mx, red, tid);
    bool no_nom = (num == 0.f);
    bool over = (gmx > ub);
#pragma unroll
    for (int k = 0; k < 4; ++k) {
      float nxt = no_nom ? wc[k] : (over ? fminf(fmaxf(wcn[k], lb), ub) : wcn[k]);
      float oldn = no_nom ? old_[k] : wcn[k];
      wc[k] = nxt;
      old_[k] = oldn;
    }
    done = no_nom || !over;
  }
#pragma unroll
  for (int k = 0; k < 4; ++k) out[row * 1024 + tid * 4 + k] = wc[k];
}

// ---------------- host ----------------
extern "C" void kernel_launch(void* const* d_in, const int* in_sizes, int n_in,
                              void* d_out, int out_size, void* d_ws, size_t ws_size,
                              hipStream_t stream) {
  const float* x      = (const float*)d_in[0];
  const float* wih[2] = {(const float*)d_in[1], (const float*)d_in[5]};
  const float* whh[2] = {(const float*)d_in[2], (const float*)d_in[6]};
  const float* bih[2] = {(const float*)d_in[3], (const float*)d_in[7]};
  const float* bhh[2] = {(const float*)d_in[4], (const float*)d_in[8]};
  const float* fcw    = (const float*)d_in[9];
  const float* fcb    = (const float*)d_in[10];
  float* outp = (float*)d_out;

  unsigned char* ws = (unsigned char*)d_ws;
  size_t off = 0;
  auto alloc = [&](size_t bytes) -> void* {
    void* p = ws + off;
    off += (bytes + 255) & ~(size_t)255;
    return p;
  };
  bft* xb      = (bft*)alloc((size_t)BB * TT * DD * 2);   // x bf16; becomes layer-0 h-seq
  bft* wihb0   = (bft*)alloc((size_t)G3 * DD * 2);
  bft* whhb0   = (bft*)alloc((size_t)G3 * HH * 2);
  bft* wihb1   = (bft*)alloc((size_t)G3 * HH * 2);
  bft* whhb1   = (bft*)alloc((size_t)G3 * HH * 2);
  bft* fcwb    = (bft*)alloc((size_t)1024 * 1024 * 2);
  bft* xp      = (bft*)alloc((size_t)BB * TC * G3 * 2);   // chunk x_proj
  bft* hb0     = (bft*)alloc((size_t)BB * HH * 2);
  bft* hb1     = (bft*)alloc((size_t)BB * HH * 2);
  float* hf0   = (float*)alloc((size_t)BB * HH * 4);
  float* hf1   = (float*)alloc((size_t)BB * HH * 4);
  float* logits= (float*)alloc((size_t)BB * 1024 * 4);
  if (off > ws_size) return;  // insufficient workspace: leave output poisoned

  bft* wihb[2] = {wihb0, wihb1};
  bft* whhb[2] = {whhb0, whhb1};

  // converts
  k_cvt<<<dim3(4096), dim3(256), 0, stream>>>(x, xb, (long)BB * TT * DD);
  k_cvt<<<dim3(1536), dim3(256), 0, stream>>>(wih[0], wihb[0], (long)G3 * DD);
  k_cvt<<<dim3(1536), dim3(256), 0, stream>>>(whh[0], whhb[0], (long)G3 * HH);
  k_cvt<<<dim3(1536), dim3(256), 0, stream>>>(wih[1], wihb[1], (long)G3 * HH);
  k_cvt<<<dim3(1536), dim3(256), 0, stream>>>(whh[1], whhb[1], (long)G3 * HH);
  k_cvt<<<dim3(512),  dim3(256), 0, stream>>>(fcw, fcwb, (long)1024 * 1024);

  for (int l = 0; l < 2; ++l) {
    hipMemsetAsync(hb1, 0, (size_t)BB * HH * 2, stream);
    hipMemsetAsync(hf1, 0, (size_t)BB * HH * 4, stream);
    for (int c = 0; c < NCH; ++c) {
      int t0 = c * TC;
      // x_proj for this chunk: M = BB*TC = 16384, N = 3072, K = 1024
      k_gemm<true, 0><<<dim3(G3 / 128, (BB * TC) / 128), 256, 0, stream>>>(
          xb, DD, wihb[l], DD, bih[l], xp, G3, t0, DD);
      // persistent 32-step chunk
      const bft* a_whh = whhb[l];
      const float* a_bhh = bhh[l];
      const bft* a_xp = xp;
      bft* a_xseq = xb;
      bft* a_hb0 = hb0; bft* a_hb1 = hb1;
      float* a_hf0 = hf0; float* a_hf1 = hf1;
      int a_t0 = t0;
      void* kargs[] = {&a_whh, &a_bhh, &a_xp, &a_xseq,
                       &a_hb0, &a_hb1, &a_hf0, &a_hf1, &a_t0};
      void* kfun = (l == 0) ? reinterpret_cast<void*>(&k_persist<0>)
                            : reinterpret_cast<void*>(&k_persist<1>);
      hipLaunchCooperativeKernel(kfun, dim3(256), dim3(256), kargs, 0, stream);
    }
  }
  // FC + SiLU: final h (bf16) of layer 1 is hb1 (t=127 odd)
  k_gemm<false, 1><<<dim3(1024 / 128, BB / 128), 256, 0, stream>>>(
      hb1, HH, fcwb, HH, fcb, logits, 1024, 0, HH);
  k_smrebal<<<dim3(BB), 256, 0, stream>>>(logits, outp);
}

// Round 3
// 4481.456 us; speedup vs baseline: 3.6878x; 3.6878x over previous
//
#include <hip/hip_runtime.h>
#include <hip/hip_bf16.h>
#include <stdint.h>

// Sizes (fixed by the problem)
#define BB 512      // batch
#define TT 128      // seq len
#define DD 1024     // input dim / hidden
#define HH 1024
#define G3 3072     // 3*H
#define TC 32       // time chunk
#define NCH (TT/TC)

typedef __bf16 bft;
typedef __bf16 bf16x8 __attribute__((ext_vector_type(8)));
typedef float f32x4 __attribute__((ext_vector_type(4)));

// async global->LDS, 16B per lane. lds base must be wave-uniform; lane i's data
// lands at base + i*16, so lane i's global ptr must be the data for that slot.
__device__ __forceinline__ void gl_lds16(const bft* g, void* lds_base_uniform) {
  __builtin_amdgcn_global_load_lds(
      (const __attribute__((address_space(1))) void*)g,
      (__attribute__((address_space(3))) void*)lds_base_uniform,
      16, 0, 0);
}

// ---------------- fp32 -> bf16 convert (vectorized 8/thread) ----------------
__global__ void k_cvt(const float* __restrict__ in, bft* __restrict__ out, long n) {
  long i = ((long)blockIdx.x * blockDim.x + threadIdx.x) * 8;
  long stride = (long)gridDim.x * blockDim.x * 8;
  for (; i < n; i += stride) {
    float4 a = *(const float4*)(in + i);
    float4 b = *(const float4*)(in + i + 4);
    bf16x8 r;
    r[0] = (bft)a.x; r[1] = (bft)a.y; r[2] = (bft)a.z; r[3] = (bft)a.w;
    r[4] = (bft)b.x; r[5] = (bft)b.y; r[6] = (bft)b.z; r[7] = (bft)b.w;
    *(bf16x8*)(out + i) = r;
  }
}

// ---------------- generic bf16 GEMM: C[m,n] = sum_k A[m,k]*W[n,k] + bias[n] --
// BM=BN=128, BK=64, 256 threads (4 waves as 2x2, each wave 64x64 = 4x4 frags).
// CHUNKED: A row m maps to global row (m>>5)*TT + t0 + (m&31)  (b,t packing).
// EPI==0: store bf16 (x_proj). EPI==1: store fp32 silu(v) (logits).
template<bool CHUNKED, int EPI>
__launch_bounds__(256)
__global__ void k_gemm(const bft* __restrict__ A, long lda,
                       const bft* __restrict__ W, long ldw,
                       const float* __restrict__ bias,
                       void* __restrict__ Cout, long ldc,
                       int t0, int K) {
  __shared__ unsigned char sm[32768];   // A tile 16KB | W tile 16KB
  const int tid  = threadIdx.x;
  const int lane = tid & 63;
  const int wid  = tid >> 6;
  const int m0 = blockIdx.y * 128;
  const int n0 = blockIdx.x * 128;
  const int wm = wid >> 1, wn = wid & 1;

  f32x4 acc[4][4] = {};

  for (int k0 = 0; k0 < K; k0 += 64) {
#pragma unroll
    for (int s = 0; s < 4; ++s) {
      int seg = wid * 4 + s;
      int row = seg * 8 + (lane >> 3);
      int cbs = ((lane & 7) * 16) ^ ((row & 7) << 4);
      long grow = CHUNKED ? ((long)(row + m0 >> 5) * TT + t0 + ((row + m0) & 31))
                          : (long)(m0 + row);
      gl_lds16(A + grow * lda + k0 + (cbs >> 1), sm + seg * 1024);
    }
#pragma unroll
    for (int s = 0; s < 4; ++s) {
      int seg = wid * 4 + s;
      int row = seg * 8 + (lane >> 3);
      int cbs = ((lane & 7) * 16) ^ ((row & 7) << 4);
      gl_lds16(W + (long)(n0 + row) * ldw + k0 + (cbs >> 1), sm + 16384 + seg * 1024);
    }
    __syncthreads();
#pragma unroll
    for (int ks = 0; ks < 2; ++ks) {
      int kb = ks * 64 + (lane >> 4) * 16;
      bf16x8 aF[4], bF[4];
#pragma unroll
      for (int mi = 0; mi < 4; ++mi) {
        int row = wm * 64 + mi * 16 + (lane & 15);
        aF[mi] = *(const bf16x8*)(sm + row * 128 + (kb ^ ((row & 7) << 4)));
      }
#pragma unroll
      for (int ni = 0; ni < 4; ++ni) {
        int row = wn * 64 + ni * 16 + (lane & 15);
        bF[ni] = *(const bf16x8*)(sm + 16384 + row * 128 + (kb ^ ((row & 7) << 4)));
      }
#pragma unroll
      for (int mi = 0; mi < 4; ++mi)
#pragma unroll
        for (int ni = 0; ni < 4; ++ni)
          acc[mi][ni] = __builtin_amdgcn_mfma_f32_16x16x32_bf16(aF[mi], bF[ni], acc[mi][ni], 0, 0, 0);
    }
    __syncthreads();
  }

#pragma unroll
  for (int mi = 0; mi < 4; ++mi)
#pragma unroll
    for (int ni = 0; ni < 4; ++ni) {
      int col = n0 + wn * 64 + ni * 16 + (lane & 15);
      float bv = bias[col];
#pragma unroll
      for (int r = 0; r < 4; ++r) {
        long row = m0 + wm * 64 + mi * 16 + (lane >> 4) * 4 + r;
        float v = acc[mi][ni][r] + bv;
        if (EPI == 0) {
          ((bft*)Cout)[row * ldc + col] = (bft)v;
        } else {
          ((float*)Cout)[row * ldc + col] = v / (1.f + expf(-v));
        }
      }
    }
}

// ---------------- m-group barrier (64 WGs on one XCD pair) ----------------
// store+poll-all, monotonic phases, agent-scope. No contended RMW.
__device__ __forceinline__ void group_barrier(int* gslots, int myslot, int target, int tid) {
  __syncthreads();   // all 4 waves done (compiler drains vmem before s_barrier)
  if (tid < 64) {
    __builtin_amdgcn_fence(__ATOMIC_RELEASE, "agent");   // flush my XCD L2 dirty lines
    if (tid == 0)
      __hip_atomic_store(&gslots[myslot], target, __ATOMIC_RELAXED, __HIP_MEMORY_SCOPE_AGENT);
    while (__hip_atomic_load(&gslots[tid], __ATOMIC_RELAXED, __HIP_MEMORY_SCOPE_AGENT) < target)
      __builtin_amdgcn_s_sleep(1);
    __builtin_amdgcn_fence(__ATOMIC_ACQUIRE, "agent");   // invalidate stale lines
  }
  __syncthreads();
}

// ---------------- persistent GRU chunk kernel (plain launch) ----------------
// 256 WGs = 4 m-groups x 64 j-tiles. mt=(xcd)>>1 -> each group owns an XCD PAIR;
// barriers are per-group (64 WGs), groups never sync with each other.
// Each WG: W_hh slice (48x1024, 96KB swizzled) stationary in LDS; A (h_prev
// 128x1024) staged per step through a 3-deep LDS pipeline with counted vmcnt.
// h_prev fp32 carried in REGISTERS across steps (hfc only at chunk boundaries).
template<int L>
__launch_bounds__(256, 1)
__global__ void k_persist(const bft* __restrict__ whh, const float* __restrict__ bhh,
                          const bft* __restrict__ xp, bft* __restrict__ xseq,
                          bft* __restrict__ hb0, bft* __restrict__ hb1,
                          float* __restrict__ hfc, int* __restrict__ slots,
                          int t0, int pbase) {
  __shared__ unsigned char sm[147456];          // W 96KB | A 3x16KB
  unsigned char* smW = sm;
  unsigned char* smA = sm + 98304;

  const int tid  = threadIdx.x;
  const int lane = tid & 63;
  const int wid  = tid >> 6;
  const int bid  = blockIdx.x;
  const int xcd = bid & 7, loc = bid >> 3;
  const int mt = xcd >> 1;                // m-group = XCD pair
  const int nt = (xcd & 1) * 32 + loc;    // 0..63 j-tile within group
  const int j0 = nt * 16;
  const int m0 = mt * 128;
  const int j  = j0 + (lane & 15);
  int* gslots = slots + mt * 64;

  // ---- load W slice into LDS (once): rows r in [0,48): gate r>>4, col j0+(r&15)
#pragma unroll
  for (int s8 = 0; s8 < 24; ++s8) {
    int s = wid * 24 + s8;
    int row = s >> 1;
    int half = s & 1;
    int hb = half * 1024 + lane * 16;               // byte within 2048B row
    int sb = hb ^ ((row & 7) << 4);                 // pre-swizzled source byte
    long grow = (long)(row >> 4) * 1024 + j0 + (row & 15);
    gl_lds16(whh + grow * 1024 + (sb >> 1), smW + s * 1024);
  }
  asm volatile("s_waitcnt vmcnt(0)" ::: "memory");
  __builtin_amdgcn_s_barrier();

  const float br = bhh[j], bz = bhh[1024 + j], bn = bhh[2048 + j];

  auto stageA = [&](const bft* base, long stride, int k0, int bufsel) {
    unsigned char* dst = smA + bufsel * 16384;
#pragma unroll
    for (int si = 0; si < 4; ++si) {
      int seg = wid * 4 + si;
      int row = seg * 8 + (lane >> 3);
      int cb = ((lane & 7) * 16) ^ ((row & 7) << 4);
      gl_lds16(base + (long)(m0 + row) * stride + k0 + (cb >> 1), dst + seg * 1024);
    }
  };

  float xg[3][2][4];   // x_proj gate operands for the CURRENT step (prefetched)
  float hp[2][4];      // register-carried fp32 h_prev for this WG's 128x16 slice

  auto prefXG = [&](int s) {
#pragma unroll
    for (int mi = 0; mi < 2; ++mi)
#pragma unroll
      for (int r = 0; r < 4; ++r) {
        long b = m0 + wid * 32 + mi * 16 + (lane >> 4) * 4 + r;
        long xrow = (b * TC + s) * (long)G3 + j;
        xg[0][mi][r] = (float)xp[xrow];
        xg[1][mi][r] = (float)xp[xrow + 1024];
        xg[2][mi][r] = (float)xp[xrow + 2048];
      }
  };

  prefXG(0);
  if (t0 == 0) {
#pragma unroll
    for (int mi = 0; mi < 2; ++mi)
#pragma unroll
      for (int r = 0; r < 4; ++r) hp[mi][r] = 0.f;
  } else {
#pragma unroll
    for (int mi = 0; mi < 2; ++mi)
#pragma unroll
      for (int r = 0; r < 4; ++r) {
        long b = m0 + wid * 32 + mi * 16 + (lane >> 4) * 4 + r;
        hp[mi][r] = hfc[b * HH + j];
      }
  }
  __builtin_amdgcn_sched_barrier(0);

  for (int s = 0; s < TC; ++s) {
    const int t = t0 + s;

    const bft* Ab; long Ast;
    if (L == 0) {
      if (t == 0) { Ab = hb1; Ast = HH; }
      else        { Ab = xseq + (long)(t - 1) * DD; Ast = (long)TT * DD; }
    } else {
      Ab = (t & 1) ? hb0 : hb1; Ast = HH;
    }

    stageA(Ab, Ast, 0, 0);
    stageA(Ab, Ast, 64, 1);

    f32x4 acc[3][2] = {};
#pragma unroll
    for (int k = 0; k < 16; ++k) {
      __builtin_amdgcn_s_barrier();               // prev-iter LDS reads done
      if (k < 14) stageA(Ab, Ast, (k + 2) * 64, (k + 2) % 3);
      if (k < 14)      asm volatile("s_waitcnt vmcnt(8)" ::: "memory");
      else if (k == 14) asm volatile("s_waitcnt vmcnt(4)" ::: "memory");
      else              asm volatile("s_waitcnt vmcnt(0)" ::: "memory");
      __builtin_amdgcn_s_barrier();               // stage(k) visible to all waves
      __builtin_amdgcn_sched_barrier(0);
      const unsigned char* Abuf = smA + (k % 3) * 16384;
#pragma unroll
      for (int ks = 0; ks < 2; ++ks) {
        int kb = ks * 64 + (lane >> 4) * 16;
        bf16x8 aF[2], bF[3];
#pragma unroll
        for (int mi = 0; mi < 2; ++mi) {
          int row = wid * 32 + mi * 16 + (lane & 15);
          aF[mi] = *(const bf16x8*)(Abuf + row * 128 + (kb ^ ((row & 7) << 4)));
        }
#pragma unroll
        for (int g = 0; g < 3; ++g) {
          int wrow = g * 16 + (lane & 15);
          bF[g] = *(const bf16x8*)(smW + wrow * 2048 + ((k * 128 + kb) ^ ((wrow & 7) << 4)));
        }
#pragma unroll
        for (int g = 0; g < 3; ++g)
#pragma unroll
          for (int mi = 0; mi < 2; ++mi)
            acc[g][mi] = __builtin_amdgcn_mfma_f32_16x16x32_bf16(aF[mi], bF[g], acc[g][mi], 0, 0, 0);
      }
    }

    // epilogue: GRU cell (h_prev from registers)
#pragma unroll
    for (int mi = 0; mi < 2; ++mi)
#pragma unroll
      for (int r = 0; r < 4; ++r) {
        long b = m0 + wid * 32 + mi * 16 + (lane >> 4) * 4 + r;
        float hr = acc[0][mi][r] + br;
        float hz = acc[1][mi][r] + bz;
        float hn = acc[2][mi][r] + bn;
        float rg = 1.f / (1.f + expf(-(xg[0][mi][r] + hr)));
        float zg = 1.f / (1.f + expf(-(xg[1][mi][r] + hz)));
        float ng = tanhf(xg[2][mi][r] + rg * hn);
        float hv = (1.f - zg) * ng + zg * hp[mi][r];
        hp[mi][r] = hv;
        if (L == 0) xseq[b * (long)TT * DD + (long)t * DD + j] = (bft)hv;
        else        { bft* hbd = (t & 1) ? hb1 : hb0; hbd[b * HH + j] = (bft)hv; }
        if (s == TC - 1) hfc[b * HH + j] = hv;   // chunk-boundary h_prev spill
      }

    if (s < TC - 1) {
      prefXG(s + 1);                              // hide xp latency under barrier
      __builtin_amdgcn_sched_barrier(0);
      group_barrier(gslots, nt, pbase + s + 1, tid);
    }
  }
}

// ---------------- softmax + rebalance (one block per row) ----------------
__device__ __forceinline__ float blk_sum(float v, float* red, int tid) {
#pragma unroll
  for (int o = 32; o; o >>= 1) v += __shfl_xor(v, o);
  if ((tid & 63) == 0) red[tid >> 6] = v;
  __syncthreads();
  v = red[0] + red[1] + red[2] + red[3];
  __syncthreads();
  return v;
}
__device__ __forceinline__ float blk_max(float v, float* red, int tid) {
#pragma unroll
  for (int o = 32; o; o >>= 1) v = fmaxf(v, __shfl_xor(v, o));
  if ((tid & 63) == 0) red[tid >> 6] = v;
  __syncthreads();
  v = fmaxf(fmaxf(red[0], red[1]), fmaxf(red[2], red[3]));
  __syncthreads();
  return v;
}

__launch_bounds__(256)
__global__ void k_smrebal(const float* __restrict__ logits, float* __restrict__ out) {
  __shared__ float red[4];
  const int tid = threadIdx.x;
  const long row = blockIdx.x;
  const float ub = 0.2f, lb = 0.0f;
  float4 lv = *(const float4*)(logits + row * 1024 + tid * 4);

  float m = fmaxf(fmaxf(lv.x, lv.y), fmaxf(lv.z, lv.w));
  m = blk_max(m, red, tid);
  float e[4] = {expf(lv.x - m), expf(lv.y - m), expf(lv.z - m), expf(lv.w - m)};
  float S = blk_sum(e[0] + e[1] + e[2] + e[3], red, tid);

  float old_[4], wc[4];
#pragma unroll
  for (int k = 0; k < 4; ++k) {
    float p = e[k] / S;
    old_[k] = p;
    wc[k] = fminf(fmaxf(p, lb), ub);
  }
  bool done = false;
  for (int it = 0; it < 32 && !done; ++it) {
    float d3 = 0.f, cnt = 0.f, nsum = 0.f;
#pragma unroll
    for (int k = 0; k < 4; ++k) {
      d3 += old_[k] - wc[k];
      bool mk = (wc[k] != ub);
      cnt += mk ? 1.f : 0.f;
      nsum += mk ? wc[k] : 0.f;
    }
    float leftover = blk_sum(d3, red, tid);
    float num = blk_sum(cnt, red, tid);
    float nom_sum = blk_sum(nsum, red, tid);
    float denom = (nom_sum == 0.f) ? 1.f : nom_sum;
    float wcn[4], mx = -1e30f;
#pragma unroll
    for (int k = 0; k < 4; ++k) {
      bool mk = (wc[k] != ub);
      wcn[k] = mk ? wc[k] + leftover * wc[k] / denom : wc[k];
      mx = fmaxf(mx, wcn[k]);
    }
    float gmx = blk_max(mx, red, tid);
    bool no_nom = (num == 0.f);
    bool over = (gmx > ub);
#pragma unroll
    for (int k = 0; k < 4; ++k) {
      float nxt = no_nom ? wc[k] : (over ? fminf(fmaxf(wcn[k], lb), ub) : wcn[k]);
      float oldn = no_nom ? old_[k] : wcn[k];
      wc[k] = nxt;
      old_[k] = oldn;
    }
    done = no_nom || !over;
  }
#pragma unroll
  for (int k = 0; k < 4; ++k) out[row * 1024 + tid * 4 + k] = wc[k];
}

// ---------------- host ----------------
extern "C" void kernel_launch(void* const* d_in, const int* in_sizes, int n_in,
                              void* d_out, int out_size, void* d_ws, size_t ws_size,
                              hipStream_t stream) {
  const float* x      = (const float*)d_in[0];
  const float* wih[2] = {(const float*)d_in[1], (const float*)d_in[5]};
  const float* whh[2] = {(const float*)d_in[2], (const float*)d_in[6]};
  const float* bih[2] = {(const float*)d_in[3], (const float*)d_in[7]};
  const float* bhh[2] = {(const float*)d_in[4], (const float*)d_in[8]};
  const float* fcw    = (const float*)d_in[9];
  const float* fcb    = (const float*)d_in[10];
  float* outp = (float*)d_out;

  unsigned char* ws = (unsigned char*)d_ws;
  size_t off = 0;
  auto alloc = [&](size_t bytes) -> void* {
    void* p = ws + off;
    off += (bytes + 255) & ~(size_t)255;
    return p;
  };
  bft* xb      = (bft*)alloc((size_t)BB * TT * DD * 2);   // x bf16; becomes layer-0 h-seq
  bft* wihb0   = (bft*)alloc((size_t)G3 * DD * 2);
  bft* whhb0   = (bft*)alloc((size_t)G3 * HH * 2);
  bft* wihb1   = (bft*)alloc((size_t)G3 * HH * 2);
  bft* whhb1   = (bft*)alloc((size_t)G3 * HH * 2);
  bft* fcwb    = (bft*)alloc((size_t)1024 * 1024 * 2);
  bft* xp      = (bft*)alloc((size_t)BB * TC * G3 * 2);   // chunk x_proj
  bft* hb0     = (bft*)alloc((size_t)BB * HH * 2);
  bft* hb1     = (bft*)alloc((size_t)BB * HH * 2);
  float* hfc   = (float*)alloc((size_t)BB * HH * 4);      // chunk-boundary h fp32
  int* slots   = (int*)alloc(256 * sizeof(int));          // 4 groups x 64 slots
  float* logits= (float*)alloc((size_t)BB * 1024 * 4);
  if (off > ws_size) return;  // insufficient workspace: leave output poisoned

  bft* wihb[2] = {wihb0, wihb1};
  bft* whhb[2] = {whhb0, whhb1};

  hipMemsetAsync(slots, 0, 256 * sizeof(int), stream);
  hipMemsetAsync(hb1, 0, (size_t)BB * HH * 2, stream);

  // converts
  k_cvt<<<dim3(4096), dim3(256), 0, stream>>>(x, xb, (long)BB * TT * DD);
  k_cvt<<<dim3(1536), dim3(256), 0, stream>>>(wih[0], wihb[0], (long)G3 * DD);
  k_cvt<<<dim3(1536), dim3(256), 0, stream>>>(whh[0], whhb[0], (long)G3 * HH);
  k_cvt<<<dim3(1536), dim3(256), 0, stream>>>(wih[1], wihb[1], (long)G3 * HH);
  k_cvt<<<dim3(1536), dim3(256), 0, stream>>>(whh[1], whhb[1], (long)G3 * HH);
  k_cvt<<<dim3(512),  dim3(256), 0, stream>>>(fcw, fcwb, (long)1024 * 1024);

  for (int l = 0; l < 2; ++l) {
    for (int c = 0; c < NCH; ++c) {
      int t0 = c * TC;
      int pbase = (l * NCH + c) * 31;
      // x_proj for this chunk: M = BB*TC = 16384, N = 3072, K = 1024
      k_gemm<true, 0><<<dim3(G3 / 128, (BB * TC) / 128), 256, 0, stream>>>(
          xb, DD, wihb[l], DD, bih[l], xp, G3, t0, DD);
      if (l == 0)
        k_persist<0><<<dim3(256), dim3(256), 0, stream>>>(
            whhb[l], bhh[l], xp, xb, hb0, hb1, hfc, slots, t0, pbase);
      else
        k_persist<1><<<dim3(256), dim3(256), 0, stream>>>(
            whhb[l], bhh[l], xp, xb, hb0, hb1, hfc, slots, t0, pbase);
    }
  }
  // FC + SiLU: final h (bf16) of layer 1 is hb1 (t=127 odd)
  k_gemm<false, 1><<<dim3(1024 / 128, BB / 128), 256, 0, stream>>>(
      hb1, HH, fcwb, HH, fcb, logits, 1024, 0, HH);
  k_smrebal<<<dim3(BB), 256, 0, stream>>>(logits, outp);
}

// Round 4
// 2993.250 us; speedup vs baseline: 5.5214x; 1.4972x over previous
//
#include <hip/hip_runtime.h>
#include <hip/hip_bf16.h>
#include <stdint.h>

// Sizes (fixed by the problem)
#define BB 512      // batch
#define TT 128      // seq len
#define DD 1024     // input dim / hidden
#define HH 1024
#define G3 3072     // 3*H
#define TC 16       // time chunk (16 keeps ws ~240MB, under proven 260MB)
#define NCH (TT/TC)
#define NRING 17    // hseq2 ring slots (> TC so no address reuse within a dispatch)

typedef __bf16 bft;
typedef __bf16 bf16x8 __attribute__((ext_vector_type(8)));
typedef float f32x4 __attribute__((ext_vector_type(4)));

// async global->LDS, 16B per lane. lds base must be wave-uniform; lane i's data
// lands at base + i*16, so lane i's global ptr must be the data for that slot.
__device__ __forceinline__ void gl_lds16(const bft* g, void* lds_base_uniform) {
  __builtin_amdgcn_global_load_lds(
      (const __attribute__((address_space(1))) void*)g,
      (__attribute__((address_space(3))) void*)lds_base_uniform,
      16, 0, 0);
}

// ---- write-through (sc0 sc1: to coherence point, bypass L1/L2) stores ----
__device__ __forceinline__ void st_wt_bf16(bft* p, float v) {
  bft h = (bft)v;
  union { bft h; unsigned short u; } cv; cv.h = h;
  unsigned int uv = cv.u;
  asm volatile("global_store_short %0, %1, off sc0 sc1" :: "v"(p), "v"(uv) : "memory");
}
__device__ __forceinline__ void st_wt_f32(float* p, float v) {
  asm volatile("global_store_dword %0, %1, off sc0 sc1" :: "v"(p), "v"(v) : "memory");
}
__device__ __forceinline__ void st_wt_u32(int* p, int v) {
  asm volatile("global_store_dword %0, %1, off sc0 sc1" :: "v"(p), "v"(v) : "memory");
}
// coherent load (bypass L1/L2 -> always fresh)
__device__ __forceinline__ int ld_co_u32(const int* p) {
  int v;
  asm volatile("global_load_dword %0, %1, off sc0 sc1\n\ts_waitcnt vmcnt(0)"
               : "=v"(v) : "v"(p) : "memory");
  return v;
}

// ---------------- fp32 -> bf16 convert (vectorized 8/thread) ----------------
__global__ void k_cvt(const float* __restrict__ in, bft* __restrict__ out, long n) {
  long i = ((long)blockIdx.x * blockDim.x + threadIdx.x) * 8;
  long stride = (long)gridDim.x * blockDim.x * 8;
  for (; i < n; i += stride) {
    float4 a = *(const float4*)(in + i);
    float4 b = *(const float4*)(in + i + 4);
    bf16x8 r;
    r[0] = (bft)a.x; r[1] = (bft)a.y; r[2] = (bft)a.z; r[3] = (bft)a.w;
    r[4] = (bft)b.x; r[5] = (bft)b.y; r[6] = (bft)b.z; r[7] = (bft)b.w;
    *(bf16x8*)(out + i) = r;
  }
}

// ---- gather chunk of x (b-major [b][t][d]) into xchunk [b][tc][d] bf16 ----
__global__ void k_gather(const float* __restrict__ x, bft* __restrict__ xc, int t0) {
  long idx = (long)blockIdx.x * blockDim.x + threadIdx.x;   // one per 8 elems
  long elem = idx * 8;
  if (elem >= (long)BB * TC * DD) return;
  long m = elem >> 10;                 // packed row b*TC+tc
  int d = (int)(elem & 1023);
  long b = m >> 4; int tc = (int)(m & 15);
  const float* src = x + ((b * TT) + t0 + tc) * (long)DD + d;
  float4 a = *(const float4*)(src);
  float4 c2 = *(const float4*)(src + 4);
  bf16x8 r;
  r[0] = (bft)a.x; r[1] = (bft)a.y; r[2] = (bft)a.z; r[3] = (bft)a.w;
  r[4] = (bft)c2.x; r[5] = (bft)c2.y; r[6] = (bft)c2.z; r[7] = (bft)c2.w;
  *(bf16x8*)(xc + elem) = r;
}

// ---------------- generic bf16 GEMM: C[m,n] = sum_k A[m,k]*W[n,k] + bias[n] --
// BM=BN=128, BK=64, 256 threads (4 waves as 2x2, each wave 64x64 = 4x4 frags).
// AMODE 0: A row m at A + m*lda (packed). AMODE 2: hseq t-major: row m ->
//   (t0 + m%TC)*BB + m/TC. EPI 0: bf16 store. EPI 1: fp32 silu store.
template<int AMODE, int EPI>
__launch_bounds__(256)
__global__ void k_gemm(const bft* __restrict__ A, long lda,
                       const bft* __restrict__ W, long ldw,
                       const float* __restrict__ bias,
                       void* __restrict__ Cout, long ldc,
                       int t0, int K) {
  __shared__ unsigned char sm[32768];   // A tile 16KB | W tile 16KB
  const int tid  = threadIdx.x;
  const int lane = tid & 63;
  const int wid  = tid >> 6;
  const int m0 = blockIdx.y * 128;
  const int n0 = blockIdx.x * 128;
  const int wm = wid >> 1, wn = wid & 1;

  f32x4 acc[4][4] = {};

  for (int k0 = 0; k0 < K; k0 += 64) {
#pragma unroll
    for (int s = 0; s < 4; ++s) {
      int seg = wid * 4 + s;
      int row = seg * 8 + (lane >> 3);
      int cbs = ((lane & 7) * 16) ^ ((row & 7) << 4);
      int mr = m0 + row;
      long grow = (AMODE == 0) ? (long)mr
                               : (long)(t0 + (mr & (TC - 1))) * BB + (mr >> 4);
      gl_lds16(A + grow * lda + k0 + (cbs >> 1), sm + seg * 1024);
    }
#pragma unroll
    for (int s = 0; s < 4; ++s) {
      int seg = wid * 4 + s;
      int row = seg * 8 + (lane >> 3);
      int cbs = ((lane & 7) * 16) ^ ((row & 7) << 4);
      gl_lds16(W + (long)(n0 + row) * ldw + k0 + (cbs >> 1), sm + 16384 + seg * 1024);
    }
    __syncthreads();
#pragma unroll
    for (int ks = 0; ks < 2; ++ks) {
      int kb = ks * 64 + (lane >> 4) * 16;
      bf16x8 aF[4], bF[4];
#pragma unroll
      for (int mi = 0; mi < 4; ++mi) {
        int row = wm * 64 + mi * 16 + (lane & 15);
        aF[mi] = *(const bf16x8*)(sm + row * 128 + (kb ^ ((row & 7) << 4)));
      }
#pragma unroll
      for (int ni = 0; ni < 4; ++ni) {
        int row = wn * 64 + ni * 16 + (lane & 15);
        bF[ni] = *(const bf16x8*)(sm + 16384 + row * 128 + (kb ^ ((row & 7) << 4)));
      }
#pragma unroll
      for (int mi = 0; mi < 4; ++mi)
#pragma unroll
        for (int ni = 0; ni < 4; ++ni)
          acc[mi][ni] = __builtin_amdgcn_mfma_f32_16x16x32_bf16(aF[mi], bF[ni], acc[mi][ni], 0, 0, 0);
    }
    __syncthreads();
  }

#pragma unroll
  for (int mi = 0; mi < 4; ++mi)
#pragma unroll
    for (int ni = 0; ni < 4; ++ni) {
      int col = n0 + wn * 64 + ni * 16 + (lane & 15);
      float bv = bias[col];
#pragma unroll
      for (int r = 0; r < 4; ++r) {
        long row = m0 + wm * 64 + mi * 16 + (lane >> 4) * 4 + r;
        float v = acc[mi][ni][r] + bv;
        if (EPI == 0) {
          ((bft*)Cout)[row * ldc + col] = (bft)v;
        } else {
          ((float*)Cout)[row * ldc + col] = v / (1.f + expf(-v));
        }
      }
    }
}

// ---------------- persistent GRU chunk kernel ----------------
// 256 WGs = 4 m-groups (XCD pairs) x 64 j-tiles. W_hh slice (48x1024, 96KB,
// XOR-swizzled) stationary in LDS. A (h_prev, 128x1024 bf16) staged via 4-deep
// LDS pipeline with counted vmcnt. h fp32 carried in registers across steps.
// Sync: producers write h to a FRESH slot each step via write-through (sc0 sc1)
// stores, then set a per-WG flag; consumers poll 64 flags. No cache fences:
// within a dispatch every h address is written once before first read (ring),
// and cross-dispatch staleness is cleared by the implicit per-dispatch acquire.
template<int L>
__launch_bounds__(256, 1)
__global__ void k_persist(const bft* __restrict__ whh, const float* __restrict__ bhh,
                          const bft* __restrict__ xp,
                          bft* __restrict__ hseq,      // L0 out: [t][b][1024], 128 slots
                          bft* __restrict__ hseq2,     // L1 ring: [slot][b][1024], 17 slots
                          const bft* __restrict__ hzero,
                          float* __restrict__ hfc, int* __restrict__ flags,
                          int t0, int pbase) {
  __shared__ unsigned char sm[163840];          // W 96KB | A 4x16KB
  unsigned char* smW = sm;
  unsigned char* smA = sm + 98304;

  const int tid  = threadIdx.x;
  const int lane = tid & 63;
  const int wid  = tid >> 6;
  const int bid  = blockIdx.x;
  const int xcd = bid & 7, loc = bid >> 3;
  const int mt = xcd >> 1;                // m-group = XCD pair
  const int nt = (xcd & 1) * 32 + loc;    // 0..63 j-tile within group
  const int j0 = nt * 16;
  const int m0 = mt * 128;
  const int j  = j0 + (lane & 15);
  int* gflags = flags + mt * 64;

  // ---- load W slice into LDS (once): rows r in [0,48): gate r>>4, col j0+(r&15)
#pragma unroll
  for (int s8 = 0; s8 < 24; ++s8) {
    int s = wid * 24 + s8;
    int row = s >> 1;
    int half = s & 1;
    int hb = half * 1024 + lane * 16;               // byte within 2048B row
    int sb = hb ^ ((row & 7) << 4);                 // pre-swizzled source byte
    long grow = (long)(row >> 4) * 1024 + j0 + (row & 15);
    gl_lds16(whh + grow * 1024 + (sb >> 1), smW + s * 1024);
  }
  asm volatile("s_waitcnt vmcnt(0)" ::: "memory");
  __builtin_amdgcn_s_barrier();

  const float br = bhh[j], bz = bhh[1024 + j], bn = bhh[2048 + j];

  auto stageA = [&](const bft* base, int k0, int bufsel) {
    unsigned char* dst = smA + bufsel * 16384;
#pragma unroll
    for (int si = 0; si < 4; ++si) {
      int seg = wid * 4 + si;
      int row = seg * 8 + (lane >> 3);
      int cb = ((lane & 7) * 16) ^ ((row & 7) << 4);
      gl_lds16(base + (long)(m0 + row) * DD + k0 + (cb >> 1), dst + seg * 1024);
    }
  };

  float xg[3][2][4];   // x_proj gate operands for the CURRENT step (prefetched)
  float hp[2][4];      // register-carried fp32 h_prev for this WG's 128x16 slice

  auto prefXG = [&](int s) {
#pragma unroll
    for (int mi = 0; mi < 2; ++mi)
#pragma unroll
      for (int r = 0; r < 4; ++r) {
        long b = m0 + wid * 32 + mi * 16 + (lane >> 4) * 4 + r;
        long xrow = (b * TC + s) * (long)G3 + j;
        xg[0][mi][r] = (float)xp[xrow];
        xg[1][mi][r] = (float)xp[xrow + 1024];
        xg[2][mi][r] = (float)xp[xrow + 2048];
      }
  };

  prefXG(0);
  if (t0 == 0) {
#pragma unroll
    for (int mi = 0; mi < 2; ++mi)
#pragma unroll
      for (int r = 0; r < 4; ++r) hp[mi][r] = 0.f;
  } else {
#pragma unroll
    for (int mi = 0; mi < 2; ++mi)
#pragma unroll
      for (int r = 0; r < 4; ++r) {
        long b = m0 + wid * 32 + mi * 16 + (lane >> 4) * 4 + r;
        hp[mi][r] = hfc[b * HH + j];
      }
  }
  __builtin_amdgcn_sched_barrier(0);

  for (int s = 0; s < TC; ++s) {
    const int t = t0 + s;

    if (s) {   // wait for step s-1 producers of my m-group
      int target = pbase + s;
      if (tid < 64) {
        const int* fp = gflags + tid;
        while (ld_co_u32(fp) < target) __builtin_amdgcn_s_sleep(2);
      }
      __syncthreads();
    }

    const bft* Ab;
    if (L == 0) Ab = (t == 0) ? hzero : hseq  + (long)(t - 1) * (BB * (long)DD);
    else        Ab = (t == 0) ? hzero : hseq2 + (long)((t - 1) % NRING) * (BB * (long)DD);

    stageA(Ab, 0, 0);
    stageA(Ab, 64, 1);
    stageA(Ab, 128, 2);

    f32x4 acc[3][2] = {};
#pragma unroll
    for (int k = 0; k < 16; ++k) {
      __builtin_amdgcn_s_barrier();               // prev-iter LDS reads done
      if (k < 13) stageA(Ab, (k + 3) * 64, (k + 3) & 3);
      if (k < 13)       asm volatile("s_waitcnt vmcnt(12)" ::: "memory");
      else if (k == 13) asm volatile("s_waitcnt vmcnt(8)" ::: "memory");
      else if (k == 14) asm volatile("s_waitcnt vmcnt(4)" ::: "memory");
      else              asm volatile("s_waitcnt vmcnt(0)" ::: "memory");
      __builtin_amdgcn_s_barrier();               // stage(k) visible to all waves
      __builtin_amdgcn_sched_barrier(0);
      const unsigned char* Abuf = smA + (k & 3) * 16384;
#pragma unroll
      for (int ks = 0; ks < 2; ++ks) {
        int kb = ks * 64 + (lane >> 4) * 16;
        bf16x8 aF[2], bF[3];
#pragma unroll
        for (int mi = 0; mi < 2; ++mi) {
          int row = wid * 32 + mi * 16 + (lane & 15);
          aF[mi] = *(const bf16x8*)(Abuf + row * 128 + (kb ^ ((row & 7) << 4)));
        }
#pragma unroll
        for (int g = 0; g < 3; ++g) {
          int wrow = g * 16 + (lane & 15);
          bF[g] = *(const bf16x8*)(smW + wrow * 2048 + ((k * 128 + kb) ^ ((wrow & 7) << 4)));
        }
#pragma unroll
        for (int g = 0; g < 3; ++g)
#pragma unroll
          for (int mi = 0; mi < 2; ++mi)
            acc[g][mi] = __builtin_amdgcn_mfma_f32_16x16x32_bf16(aF[mi], bF[g], acc[g][mi], 0, 0, 0);
      }
    }

    // epilogue: GRU cell (h_prev from registers), write-through h stores
    bft* outp = (L == 0) ? hseq  + (long)t * (BB * (long)DD)
                         : hseq2 + (long)(t % NRING) * (BB * (long)DD);
#pragma unroll
    for (int mi = 0; mi < 2; ++mi)
#pragma unroll
      for (int r = 0; r < 4; ++r) {
        long b = m0 + wid * 32 + mi * 16 + (lane >> 4) * 4 + r;
        float hr = acc[0][mi][r] + br;
        float hz = acc[1][mi][r] + bz;
        float hn = acc[2][mi][r] + bn;
        float rg = 1.f / (1.f + expf(-(xg[0][mi][r] + hr)));
        float zg = 1.f / (1.f + expf(-(xg[1][mi][r] + hz)));
        float ng = tanhf(xg[2][mi][r] + rg * hn);
        float hv = (1.f - zg) * ng + zg * hp[mi][r];
        hp[mi][r] = hv;
        st_wt_bf16(outp + b * DD + j, hv);
        if (s == TC - 1) st_wt_f32(hfc + b * HH + j, hv);
      }

    __syncthreads();   // per-wave vmcnt(0) drain before barrier => stores visible
    if (s < TC - 1) {
      if (tid == 0) st_wt_u32(gflags + nt, pbase + s + 1);
      prefXG(s + 1);   // hide xp latency under next step's flag wait
      __builtin_amdgcn_sched_barrier(0);
    }
  }
}

// ---------------- softmax + rebalance (one block per row) ----------------
__device__ __forceinline__ float blk_sum(float v, float* red, int tid) {
#pragma unroll
  for (int o = 32; o; o >>= 1) v += __shfl_xor(v, o);
  if ((tid & 63) == 0) red[tid >> 6] = v;
  __syncthreads();
  v = red[0] + red[1] + red[2] + red[3];
  __syncthreads();
  return v;
}
__device__ __forceinline__ float blk_max(float v, float* red, int tid) {
#pragma unroll
  for (int o = 32; o; o >>= 1) v = fmaxf(v, __shfl_xor(v, o));
  if ((tid & 63) == 0) red[tid >> 6] = v;
  __syncthreads();
  v = fmaxf(fmaxf(red[0], red[1]), fmaxf(red[2], red[3]));
  __syncthreads();
  return v;
}

__launch_bounds__(256)
__global__ void k_smrebal(const float* __restrict__ logits, float* __restrict__ out) {
  __shared__ float red[4];
  const int tid = threadIdx.x;
  const long row = blockIdx.x;
  const float ub = 0.2f, lb = 0.0f;
  float4 lv = *(const float4*)(logits + row * 1024 + tid * 4);

  float m = fmaxf(fmaxf(lv.x, lv.y), fmaxf(lv.z, lv.w));
  m = blk_max(m, red, tid);
  float e[4] = {expf(lv.x - m), expf(lv.y - m), expf(lv.z - m), expf(lv.w - m)};
  float S = blk_sum(e[0] + e[1] + e[2] + e[3], red, tid);

  float old_[4], wc[4];
#pragma unroll
  for (int k = 0; k < 4; ++k) {
    float p = e[k] / S;
    old_[k] = p;
    wc[k] = fminf(fmaxf(p, lb), ub);
  }
  bool done = false;
  for (int it = 0; it < 32 && !done; ++it) {
    float d3 = 0.f, cnt = 0.f, nsum = 0.f;
#pragma unroll
    for (int k = 0; k < 4; ++k) {
      d3 += old_[k] - wc[k];
      bool mk = (wc[k] != ub);
      cnt += mk ? 1.f : 0.f;
      nsum += mk ? wc[k] : 0.f;
    }
    float leftover = blk_sum(d3, red, tid);
    float num = blk_sum(cnt, red, tid);
    float nom_sum = blk_sum(nsum, red, tid);
    float denom = (nom_sum == 0.f) ? 1.f : nom_sum;
    float wcn[4], mx = -1e30f;
#pragma unroll
    for (int k = 0; k < 4; ++k) {
      bool mk = (wc[k] != ub);
      wcn[k] = mk ? wc[k] + leftover * wc[k] / denom : wc[k];
      mx = fmaxf(mx, wcn[k]);
    }
    float gmx = blk_max(mx, red, tid);
    bool no_nom = (num == 0.f);
    bool over = (gmx > ub);
#pragma unroll
    for (int k = 0; k < 4; ++k) {
      float nxt = no_nom ? wc[k] : (over ? fminf(fmaxf(wcn[k], lb), ub) : wcn[k]);
      float oldn = no_nom ? old_[k] : wcn[k];
      wc[k] = nxt;
      old_[k] = oldn;
    }
    done = no_nom || !over;
  }
#pragma unroll
  for (int k = 0; k < 4; ++k) out[row * 1024 + tid * 4 + k] = wc[k];
}

// ---------------- host ----------------
extern "C" void kernel_launch(void* const* d_in, const int* in_sizes, int n_in,
                              void* d_out, int out_size, void* d_ws, size_t ws_size,
                              hipStream_t stream) {
  const float* x      = (const float*)d_in[0];
  const float* wih[2] = {(const float*)d_in[1], (const float*)d_in[5]};
  const float* whh[2] = {(const float*)d_in[2], (const float*)d_in[6]};
  const float* bih[2] = {(const float*)d_in[3], (const float*)d_in[7]};
  const float* bhh[2] = {(const float*)d_in[4], (const float*)d_in[8]};
  const float* fcw    = (const float*)d_in[9];
  const float* fcb    = (const float*)d_in[10];
  float* outp = (float*)d_out;

  unsigned char* ws = (unsigned char*)d_ws;
  size_t off = 0;
  auto alloc = [&](size_t bytes) -> void* {
    void* p = ws + off;
    off += (bytes + 255) & ~(size_t)255;
    return p;
  };
  bft* xchunk  = (bft*)alloc((size_t)BB * TC * DD * 2);       // 16MB, packed chunk of x
  bft* wihb0   = (bft*)alloc((size_t)G3 * DD * 2);
  bft* whhb0   = (bft*)alloc((size_t)G3 * HH * 2);
  bft* wihb1   = (bft*)alloc((size_t)G3 * HH * 2);
  bft* whhb1   = (bft*)alloc((size_t)G3 * HH * 2);
  bft* fcwb    = (bft*)alloc((size_t)1024 * 1024 * 2);
  bft* xp      = (bft*)alloc((size_t)BB * TC * G3 * 2);       // 48MB chunk x_proj
  bft* hseq    = (bft*)alloc((size_t)TT * BB * DD * 2);       // 128MB, [t][b][d] L0 h
  bft* hseq2   = (bft*)alloc((size_t)NRING * BB * DD * 2);    // 17MB, L1 h ring
  bft* hzero   = (bft*)alloc((size_t)BB * DD * 2);            // 1MB zeros
  float* hfc   = (float*)alloc((size_t)BB * HH * 4);          // chunk-boundary h fp32
  int* flags   = (int*)alloc(1024);                           // 4 groups x 64 slots
  float* logits= (float*)alloc((size_t)BB * 1024 * 4);
  if (off > ws_size) return;  // insufficient workspace: leave output poisoned

  bft* wihb[2] = {wihb0, wihb1};
  bft* whhb[2] = {whhb0, whhb1};

  hipMemsetAsync(flags, 0, 1024, stream);
  hipMemsetAsync(hzero, 0, (size_t)BB * DD * 2, stream);

  // weight converts
  k_cvt<<<dim3(1536), dim3(256), 0, stream>>>(wih[0], wihb[0], (long)G3 * DD);
  k_cvt<<<dim3(1536), dim3(256), 0, stream>>>(whh[0], whhb[0], (long)G3 * HH);
  k_cvt<<<dim3(1536), dim3(256), 0, stream>>>(wih[1], wihb[1], (long)G3 * HH);
  k_cvt<<<dim3(1536), dim3(256), 0, stream>>>(whh[1], whhb[1], (long)G3 * HH);
  k_cvt<<<dim3(512),  dim3(256), 0, stream>>>(fcw, fcwb, (long)1024 * 1024);

  for (int l = 0; l < 2; ++l) {
    for (int c = 0; c < NCH; ++c) {
      int t0 = c * TC;
      int pbase = (l * NCH + c) * TC;
      if (l == 0) {
        k_gather<<<dim3(4096), dim3(256), 0, stream>>>(x, xchunk, t0);
        k_gemm<0, 0><<<dim3(G3 / 128, (BB * TC) / 128), 256, 0, stream>>>(
            xchunk, DD, wihb[0], DD, bih[0], xp, G3, t0, DD);
        k_persist<0><<<dim3(256), dim3(256), 0, stream>>>(
            whhb[0], bhh[0], xp, hseq, hseq2, hzero, hfc, flags, t0, pbase);
      } else {
        k_gemm<2, 0><<<dim3(G3 / 128, (BB * TC) / 128), 256, 0, stream>>>(
            hseq, DD, wihb[1], DD, bih[1], xp, G3, t0, DD);
        k_persist<1><<<dim3(256), dim3(256), 0, stream>>>(
            whhb[1], bhh[1], xp, hseq, hseq2, hzero, hfc, flags, t0, pbase);
      }
    }
  }
  // FC + SiLU on final h (t=127 -> ring slot 127%17 = 8)
  const bft* hfin = hseq2 + (size_t)((TT - 1) % NRING) * BB * DD;
  k_gemm<0, 1><<<dim3(1024 / 128, BB / 128), 256, 0, stream>>>(
      hfin, DD, fcwb, HH, fcb, logits, 1024, 0, HH);
  k_smrebal<<<dim3(BB), 256, 0, stream>>>(logits, outp);
}